// Round 8
// baseline (1499.115 us; speedup 1.0000x reference)
//
#include <hip/hip_runtime.h>
#include <cstdint>
#include <cstddef>

// ---------------------------------------------------------------------------
// Llama4-style MoE experts, MI355X (gfx950).
//   gemm1 : per expert [1024x2048]x[2048x8192] -> SwiGLU -> act bf16 (ws)
//   gemm2 : act[1024xF] x W2[Fx2048] -> out fp32 (accumulating when chunked)
// Weights fp32->bf16 on the fly during LDS staging (B loaded coalesced in
// transposed order -> column-major LDS tile; both operand frags are
// contiguous bf16x8 along K).  fp32 accumulation via mfma_f32_16x16x32_bf16.
//
// LDS tiles: 64B rows (32 k * bf16), XOR swizzle byte^=((row>>1)&3)<<4
// (uniform bank load for 16B writes and b128 frag reads).
//
// ws ladder (act scratch sized to what the harness actually gives us):
//   >=96MiB : cvt_h(H->bf16) + all-expert gemm1<PRE>/gemm2     (fast path)
//   >=64MiB : all-expert gemm1<!PRE>/gemm2
//   >= 8MiB : per-expert sequential (act chunk FC=4096)
//   >=128KiB: per-expert, f-chunked (FC = pow2 in [64,2048]); out zeroed,
//             gemm2 accumulates per chunk (stream-serialized, race-free)
// ---------------------------------------------------------------------------

typedef __attribute__((ext_vector_type(4))) float  f32x4;
typedef __attribute__((ext_vector_type(8))) __bf16 bf16x8;

#define MFMA(A, B, C) __builtin_amdgcn_mfma_f32_16x16x32_bf16((A), (B), (C), 0, 0, 0)

// ---------------------------------------------------------------------------
__global__ __launch_bounds__(256)
void cvt_h(const float* __restrict__ H, __bf16* __restrict__ Hb)
{
    const size_t i = ((size_t)blockIdx.x * 256 + threadIdx.x) * 8;
    const f32x4 a = *(const f32x4*)(H + i);
    const f32x4 b = *(const f32x4*)(H + i + 4);
    bf16x8 o;
    o[0] = (__bf16)a[0]; o[1] = (__bf16)a[1]; o[2] = (__bf16)a[2]; o[3] = (__bf16)a[3];
    o[4] = (__bf16)b[0]; o[5] = (__bf16)b[1]; o[6] = (__bf16)b[2]; o[7] = (__bf16)b[3];
    *(bf16x8*)(Hb + i) = o;
}

// ---------------------------------------------------------------------------
// GEMM1 + SwiGLU.  grid = (FC/64 fb, 4 mb, Ne), 256 threads (4 waves, 2x2).
// Block tile: 256 rows x 128 B-cols (= 64 f output cols), BK=32, 64 K-iters.
// Expert e0+bz reads H/W1; act indexed by local expert bz with row stride
// fstride, local cols bx*64..bx*64+63 (global f = f0base + local).
// Wave tile 128x64: acc[8][4]; n=0,1 -> gate, n=2,3 -> up (lane-local SwiGLU).
// ---------------------------------------------------------------------------
template <bool PRE>
__global__ __launch_bounds__(256, 2)
void moe_gemm1(const __bf16* __restrict__ Hb, const float* __restrict__ Hf,
               const float* __restrict__ W1, __bf16* __restrict__ act,
               int e0, int f0base, int fstride)
{
    const int eg   = e0 + blockIdx.z;        // input expert
    const int el   = blockIdx.z;             // act-chunk expert
    const int mb   = blockIdx.y;
    const int bx   = blockIdx.x;
    const int row0 = mb * 256;
    const int f0   = f0base + bx * 64;       // W1 gate col base (global)

    __shared__ __bf16 As[2][256 * 32];   // [row][k], 64B rows, swizzled
    __shared__ __bf16 Bs[2][128 * 32];   // column-major [col][k], swizzled

    const int tid  = threadIdx.x;
    const int lane = tid & 63;
    const int wid  = tid >> 6;
    const int wr   = wid >> 1;
    const int wc   = wid & 1;
    const int g    = lane >> 4;
    const int l15  = lane & 15;

    // ---- A staging: one row per thread (256 rows), all 32 k ----
    const __bf16* aptr  = Hb + (size_t)(eg * 1024 + row0 + tid) * 2048;
    const float*  aptrf = Hf + (size_t)(eg * 1024 + row0 + tid) * 2048;
    const uint32_t a_w   = (uint32_t)(tid * 64);
    const uint32_t a_swz = (uint32_t)(((tid >> 1) & 3) << 4);

    // ---- B staging: col c = tid&127, k-half = tid>>7 (16 k each) ----
    const int c  = tid & 127;
    const int kh = tid >> 7;
    const int cc = c & 63;
    const int gucol = f0 + ((c >> 6) << 5) + ((cc < 32) ? cc : (4096 + cc - 32));
    const float* bptr = W1 + (size_t)eg * 2048 * 8192 + (size_t)(kh * 16) * 8192 + gucol;
    const uint32_t b_w   = (uint32_t)(c * 64);
    const uint32_t b_swz = (uint32_t)(((c >> 1) & 3) << 4);

    // ---- fragment read offsets ----
    const uint32_t sw  = (uint32_t)(((l15 >> 1) & 3) << 4);
    const uint32_t a_r = (uint32_t)(wr * 8192 + l15 * 64 + ((g * 16) ^ sw));  // + m*1024
    const uint32_t b_r = (uint32_t)(wc * 4096 + l15 * 64 + ((g * 16) ^ sw));  // + n*1024

    f32x4 acc[8][4];
#pragma unroll
    for (int m = 0; m < 8; ++m)
#pragma unroll
        for (int n = 0; n < 4; ++n)
            acc[m][n] = f32x4{0.f, 0.f, 0.f, 0.f};

    bf16x8 ra[4];
    f32x4  ra32[8];
    float  rb[16];
    if constexpr (PRE) {
#pragma unroll
        for (int i = 0; i < 4; ++i) ra[i] = *(const bf16x8*)(aptr + i * 8);
    } else {
#pragma unroll
        for (int i = 0; i < 8; ++i) ra32[i] = *(const f32x4*)(aptrf + i * 4);
    }
#pragma unroll
    for (int j = 0; j < 16; ++j) rb[j] = bptr[(size_t)j * 8192];

    char* AsB = (char*)&As[0][0];
    char* BsB = (char*)&Bs[0][0];

    for (int kt = 0; kt < 64; ++kt) {
        const uint32_t ca = (uint32_t)((kt & 1) * 16384);
        const uint32_t cb = (uint32_t)((kt & 1) * 8192);

        if constexpr (PRE) {
#pragma unroll
            for (int i = 0; i < 4; ++i)
                *(bf16x8*)(AsB + ca + a_w + (((uint32_t)(i * 16)) ^ a_swz)) = ra[i];
        } else {
#pragma unroll
            for (int i = 0; i < 4; ++i) {
                bf16x8 o;
#pragma unroll
                for (int j = 0; j < 4; ++j) { o[j] = (__bf16)ra32[2 * i][j]; o[4 + j] = (__bf16)ra32[2 * i + 1][j]; }
                *(bf16x8*)(AsB + ca + a_w + (((uint32_t)(i * 16)) ^ a_swz)) = o;
            }
        }
#pragma unroll
        for (int t = 0; t < 2; ++t) {
            bf16x8 o;
#pragma unroll
            for (int j = 0; j < 8; ++j) o[j] = (__bf16)rb[t * 8 + j];
            *(bf16x8*)(BsB + cb + b_w + (((uint32_t)(kh * 32 + t * 16)) ^ b_swz)) = o;
        }
        __syncthreads();

        if (kt < 63) {
            if constexpr (PRE) {
                const __bf16* an = aptr + (kt + 1) * 32;
#pragma unroll
                for (int i = 0; i < 4; ++i) ra[i] = *(const bf16x8*)(an + i * 8);
            } else {
                const float* an = aptrf + (kt + 1) * 32;
#pragma unroll
                for (int i = 0; i < 8; ++i) ra32[i] = *(const f32x4*)(an + i * 4);
            }
            const float* bn = bptr + (size_t)(kt + 1) * 32 * 8192;
#pragma unroll
            for (int j = 0; j < 16; ++j) rb[j] = bn[(size_t)j * 8192];
        }

        bf16x8 af[8], bf[4];
#pragma unroll
        for (int m = 0; m < 8; ++m) af[m] = *(const bf16x8*)(AsB + ca + a_r + m * 1024);
#pragma unroll
        for (int n = 0; n < 4; ++n) bf[n] = *(const bf16x8*)(BsB + cb + b_r + n * 1024);

#pragma unroll
        for (int m = 0; m < 8; ++m)
#pragma unroll
            for (int n = 0; n < 4; ++n)
                acc[m][n] = MFMA(af[m], bf[n], acc[m][n]);
        // double-buffered; writes of iter kt+2 into this buffer are gated by
        // barrier(kt+1), reached only after this iter's reads.
    }

    // ---- SwiGLU epilogue: act = up * silu(gate), bf16, row stride fstride ----
    __bf16* ap = act + (size_t)(el * 1024 + row0) * fstride + bx * 64 + wc * 32;
#pragma unroll
    for (int m = 0; m < 8; ++m) {
#pragma unroll
        for (int n = 0; n < 2; ++n) {
#pragma unroll
            for (int j = 0; j < 4; ++j) {
                const int r   = wr * 128 + m * 16 + g * 4 + j;
                const int col = n * 16 + l15;
                const float gv = acc[m][n][j];
                const float uv = acc[m][n + 2][j];
                const float sv = gv / (1.0f + __expf(-gv));
                ap[(size_t)r * fstride + col] = (__bf16)(uv * sv);
            }
        }
    }
}

// ---------------------------------------------------------------------------
// GEMM2.  grid = (16 nb, 4 mb, Ne), 256 threads.  Block tile 256x128, BK=32,
// kt_n K-iters over act rows [1024 x fstride] (local expert bz) and W2 rows
// f0base .. f0base+kt_n*32-1 of global expert e0+bz.  ACCUM: out += (chunked).
// ---------------------------------------------------------------------------
template <bool ACCUM>
__global__ __launch_bounds__(256, 2)
void moe_gemm2(const __bf16* __restrict__ act, const float* __restrict__ W2,
               float* __restrict__ out, int e0, int f0base, int fstride, int kt_n)
{
    const int eg   = e0 + blockIdx.z;
    const int el   = blockIdx.z;
    const int mb   = blockIdx.y;
    const int nbx  = blockIdx.x;
    const int row0 = mb * 256;
    const int n0   = nbx * 128;

    __shared__ __bf16 As[2][256 * 32];
    __shared__ __bf16 Bs[2][128 * 32];

    const int tid  = threadIdx.x;
    const int lane = tid & 63;
    const int wid  = tid >> 6;
    const int wr   = wid >> 1;
    const int wc   = wid & 1;
    const int g    = lane >> 4;
    const int l15  = lane & 15;

    const __bf16* aptr = act + (size_t)(el * 1024 + row0 + tid) * fstride;
    const uint32_t a_w   = (uint32_t)(tid * 64);
    const uint32_t a_swz = (uint32_t)(((tid >> 1) & 3) << 4);

    const int c  = tid & 127;
    const int kh = tid >> 7;
    const float* bptr = W2 + (size_t)eg * 4096 * 2048 + (size_t)(f0base + kh * 16) * 2048 + (n0 + c);
    const uint32_t b_w   = (uint32_t)(c * 64);
    const uint32_t b_swz = (uint32_t)(((c >> 1) & 3) << 4);

    const uint32_t sw  = (uint32_t)(((l15 >> 1) & 3) << 4);
    const uint32_t a_r = (uint32_t)(wr * 8192 + l15 * 64 + ((g * 16) ^ sw));
    const uint32_t b_r = (uint32_t)(wc * 4096 + l15 * 64 + ((g * 16) ^ sw));

    f32x4 acc[8][4];
#pragma unroll
    for (int m = 0; m < 8; ++m)
#pragma unroll
        for (int n = 0; n < 4; ++n)
            acc[m][n] = f32x4{0.f, 0.f, 0.f, 0.f};

    bf16x8 ra[4];
    float  rb[16];
#pragma unroll
    for (int i = 0; i < 4; ++i) ra[i] = *(const bf16x8*)(aptr + i * 8);
#pragma unroll
    for (int j = 0; j < 16; ++j) rb[j] = bptr[(size_t)j * 2048];

    char* AsB = (char*)&As[0][0];
    char* BsB = (char*)&Bs[0][0];

    for (int kt = 0; kt < kt_n; ++kt) {
        const uint32_t ca = (uint32_t)((kt & 1) * 16384);
        const uint32_t cb = (uint32_t)((kt & 1) * 8192);

#pragma unroll
        for (int i = 0; i < 4; ++i)
            *(bf16x8*)(AsB + ca + a_w + (((uint32_t)(i * 16)) ^ a_swz)) = ra[i];
#pragma unroll
        for (int t = 0; t < 2; ++t) {
            bf16x8 o;
#pragma unroll
            for (int j = 0; j < 8; ++j) o[j] = (__bf16)rb[t * 8 + j];
            *(bf16x8*)(BsB + cb + b_w + (((uint32_t)(kh * 32 + t * 16)) ^ b_swz)) = o;
        }
        __syncthreads();

        if (kt < kt_n - 1) {
            const __bf16* an = aptr + (kt + 1) * 32;
            const float*  bn = bptr + (size_t)(kt + 1) * 32 * 2048;
#pragma unroll
            for (int i = 0; i < 4; ++i) ra[i] = *(const bf16x8*)(an + i * 8);
#pragma unroll
            for (int j = 0; j < 16; ++j) rb[j] = bn[(size_t)j * 2048];
        }

        bf16x8 af[8], bf[4];
#pragma unroll
        for (int m = 0; m < 8; ++m) af[m] = *(const bf16x8*)(AsB + ca + a_r + m * 1024);
#pragma unroll
        for (int n = 0; n < 4; ++n) bf[n] = *(const bf16x8*)(BsB + cb + b_r + n * 1024);

#pragma unroll
        for (int m = 0; m < 8; ++m)
#pragma unroll
            for (int n = 0; n < 4; ++n)
                acc[m][n] = MFMA(af[m], bf[n], acc[m][n]);
    }

    // ---- epilogue: fp32 store (or accumulate when K-chunked) ----
    float* op = out + (size_t)(eg * 1024 + row0) * 2048 + n0 + wc * 64;
#pragma unroll
    for (int m = 0; m < 8; ++m) {
#pragma unroll
        for (int n = 0; n < 4; ++n) {
#pragma unroll
            for (int j = 0; j < 4; ++j) {
                const int r = wr * 128 + m * 16 + g * 4 + j;
                float* p = op + (size_t)r * 2048 + n * 16 + l15;
                if constexpr (ACCUM) *p += acc[m][n][j];
                else                 *p  = acc[m][n][j];
            }
        }
    }
}

// ---------------------------------------------------------------------------
extern "C" void kernel_launch(void* const* d_in, const int* in_sizes, int n_in,
                              void* d_out, int out_size, void* d_ws, size_t ws_size,
                              hipStream_t stream)
{
    const float* H  = (const float*)d_in[0];   // [8192, 2048]
    const float* W1 = (const float*)d_in[1];   // [8, 2048, 8192]
    const float* W2 = (const float*)d_in[2];   // [8, 4096, 2048]
    float* out = (float*)d_out;                // [8192, 2048]
    __bf16* actb = (__bf16*)d_ws;

    (void)in_sizes; (void)n_in; (void)out_size;

    const __bf16* Hbf = (const __bf16*)H;      // placeholder for unused PRE arg

    if (ws_size >= (size_t)100663296) {
        // 96 MiB: pre-convert H once, full-grid fast path
        __bf16* Hb = (__bf16*)((char*)d_ws + 67108864);
        cvt_h<<<8192, 256, 0, stream>>>(H, Hb);
        moe_gemm1<true><<<dim3(64, 4, 8), 256, 0, stream>>>(Hb, H, W1, actb, 0, 0, 4096);
        moe_gemm2<false><<<dim3(16, 4, 8), 256, 0, stream>>>(actb, W2, out, 0, 0, 4096, 128);
    } else if (ws_size >= (size_t)67108864) {
        // 64 MiB: full-grid, A converted during staging
        moe_gemm1<false><<<dim3(64, 4, 8), 256, 0, stream>>>(Hbf, H, W1, actb, 0, 0, 4096);
        moe_gemm2<false><<<dim3(16, 4, 8), 256, 0, stream>>>(actb, W2, out, 0, 0, 4096, 128);
    } else {
        // chunked: FC f-cols per pass; act chunk = 1024*FC*2 bytes (expert-seq).
        // FC must be a power-of-two divisor of 4096 so chunks tile exactly.
        int avail = (int)(ws_size / 2048);     // max cols the ws can hold
        if (avail > 4096) avail = 4096;
        int FC = 64;                           // floor (needs >=128 KiB ws)
        while (FC * 2 <= avail) FC *= 2;
        const int nch = 4096 / FC;
        if (nch > 1)
            hipMemsetAsync(out, 0, (size_t)8192 * 2048 * 4, stream);
        for (int e = 0; e < 8; ++e) {
            for (int ch = 0; ch < nch; ++ch) {
                const int f0 = ch * FC;
                moe_gemm1<false><<<dim3(FC / 64, 4, 1), 256, 0, stream>>>(
                    Hbf, H, W1, actb, e, f0, FC);
                if (nch > 1)
                    moe_gemm2<true><<<dim3(16, 4, 1), 256, 0, stream>>>(
                        actb, W2, out, e, f0, FC, FC / 32);
                else
                    moe_gemm2<false><<<dim3(16, 4, 1), 256, 0, stream>>>(
                        actb, W2, out, e, f0, FC, FC / 32);
            }
        }
    }
}